// Round 1
// baseline (1106.767 us; speedup 1.0000x reference)
//
#include <hip/hip_runtime.h>
#include <hip/hip_bf16.h>
#include <math.h>

#define KDIM 256
#define BM 64
#define BN 64
#define BKS 16
#define RATIO_T 0.9f
#define EPS_T 1e-8f

// 1 / ||column i||  for X stored (KDIM x n) row-major (descriptors are columns)
__global__ void norms_kernel(const float* __restrict__ X, float* __restrict__ inv, int n) {
    int i = blockIdx.x * blockDim.x + threadIdx.x;
    if (i >= n) return;
    float s = 0.f;
#pragma unroll 8
    for (int k = 0; k < KDIM; ++k) {
        float v = X[(size_t)k * n + i];
        s += v * v;
    }
    inv[i] = 1.0f / sqrtf(s);
}

// Fused GEMM + per-row online top-2.
// Q, R: (KDIM x n) row-major. Block handles BM query rows (columns of Q),
// scans j in [s*chunk, (s+1)*chunk), writes partial top-2 per row per chunk.
// partial[(row)*NS + s] = (v0, v1, idx0_as_float, idx1_as_float)
__global__ __launch_bounds__(256) void gemm_top2(
    const float* __restrict__ Q, const float* __restrict__ Rm,
    const float* __restrict__ invQ, const float* __restrict__ invR,
    float4* __restrict__ partial, int n, int NS) {
    __shared__ float As[BKS][BM];
    __shared__ float Bs[BKS][BN];
    __shared__ float Sm[BM][BN + 1];   // +1 pad: scan reads (t+j)%32 -> 2-way (free)

    const int t  = threadIdx.x;
    const int tx = t & 15;
    const int ty = t >> 4;
    const int m0 = blockIdx.x * BM;
    const int s  = blockIdx.y;
    const int chunk = n / NS;
    const int jbeg = s * chunk;
    const int jend = jbeg + chunk;

    // staging coords: thread loads one float4 (4 consecutive columns) of one k-row
    const int lk = t >> 4;         // 0..15
    const int li = (t & 15) * 4;   // 0..60

    float best0 = -INFINITY, best1 = -INFINITY;
    int bi0 = -1, bi1 = -1;
    const float qinv = (t < BM) ? invQ[m0 + t] : 0.f;

    for (int jt = jbeg; jt < jend; jt += BN) {
        float acc[4][4];
#pragma unroll
        for (int a = 0; a < 4; ++a)
#pragma unroll
            for (int b = 0; b < 4; ++b) acc[a][b] = 0.f;

        for (int k0 = 0; k0 < KDIM; k0 += BKS) {
            float4 ga = *reinterpret_cast<const float4*>(&Q[(size_t)(k0 + lk) * n + m0 + li]);
            float4 gb = *reinterpret_cast<const float4*>(&Rm[(size_t)(k0 + lk) * n + jt + li]);
            __syncthreads();   // previous iteration's LDS reads complete
            *reinterpret_cast<float4*>(&As[lk][li]) = ga;
            *reinterpret_cast<float4*>(&Bs[lk][li]) = gb;
            __syncthreads();
#pragma unroll
            for (int k = 0; k < BKS; ++k) {
                float4 a4 = *reinterpret_cast<const float4*>(&As[k][ty * 4]);
                float4 b4 = *reinterpret_cast<const float4*>(&Bs[k][tx * 4]);
                float ar[4] = {a4.x, a4.y, a4.z, a4.w};
                float br[4] = {b4.x, b4.y, b4.z, b4.w};
#pragma unroll
                for (int ii = 0; ii < 4; ++ii)
#pragma unroll
                    for (int jj = 0; jj < 4; ++jj) acc[ii][jj] += ar[ii] * br[jj];
            }
        }
        // write sim tile to LDS (scalar stores: stride-65 rows, conflicts negligible)
#pragma unroll
        for (int ii = 0; ii < 4; ++ii)
#pragma unroll
            for (int jj = 0; jj < 4; ++jj)
                Sm[ty * 4 + ii][tx * 4 + jj] = acc[ii][jj];
        __syncthreads();
        // online top-2 per row, j ascending, strict '>' => lowest index on ties
        if (t < BM) {
#pragma unroll 4
            for (int j = 0; j < BN; ++j) {
                float v = Sm[t][j] * qinv * invR[jt + j];
                if (v > best0) {
                    best1 = best0; bi1 = bi0;
                    best0 = v;     bi0 = jt + j;
                } else if (v > best1) {
                    best1 = v;     bi1 = jt + j;
                }
            }
        }
        __syncthreads();
    }
    if (t < BM)
        partial[(size_t)(m0 + t) * NS + s] =
            make_float4(best0, best1, (float)bi0, (float)bi1);
}

// merge NS partial top-2 (chunks in ascending-j order; strict '>' keeps earliest)
__global__ void merge_top2(const float4* __restrict__ partial,
                           float4* __restrict__ out, int n, int NS) {
    int i = blockIdx.x * blockDim.x + threadIdx.x;
    if (i >= n) return;
    float best0 = -INFINITY, best1 = -INFINITY;
    float bi0 = -1.f, bi1 = -1.f;
    for (int s = 0; s < NS; ++s) {
        float4 p = partial[(size_t)i * NS + s];
        if (p.x > best0) {
            best1 = best0; bi1 = bi0;
            best0 = p.x;   bi0 = p.z;
        } else if (p.x > best1) {
            best1 = p.x;   bi1 = p.z;
        }
        if (p.y > best1 && p.y <= best0) {  // p.y can never exceed best0 after p.x insert
            best1 = p.y;   bi1 = p.w;
        } else if (p.y > best0) {           // defensive (shouldn't happen since p.y<=p.x)
            best1 = best0; bi1 = bi0;
            best0 = p.y;   bi0 = p.w;
        }
    }
    out[i] = make_float4(best0, best1, bi0, bi1);
}

__global__ void match_kernel(const float4* __restrict__ tAB,
                             const float4* __restrict__ tBA,
                             float* __restrict__ out, int n) {
    int i = blockIdx.x * blockDim.x + threadIdx.x;
    if (i >= n) return;
    float4 a = tAB[i];
    int j0 = (int)a.z;
    float d0 = 2.0f - 2.0f * a.x;
    float d1 = 2.0f - 2.0f * a.y;
    float r12 = d0 / (d1 + EPS_T);
    float4 b = tBA[j0];
    int nn21 = (int)b.z;
    float e0 = 2.0f - 2.0f * b.x;
    float e1 = 2.0f - 2.0f * b.y;
    float r21 = e0 / (e1 + EPS_T);
    bool m = (i == nn21) && (r12 <= RATIO_T) && (r21 <= RATIO_T);
    out[2 * i]     = m ? (float)i  : -1.0f;
    out[2 * i + 1] = m ? (float)j0 : -1.0f;
    out[2 * (size_t)n + i] = m ? a.x : 0.0f;
    out[3 * (size_t)n + i] = m ? 1.0f : 0.0f;
}

extern "C" void kernel_launch(void* const* d_in, const int* in_sizes, int n_in,
                              void* d_out, int out_size, void* d_ws, size_t ws_size,
                              hipStream_t stream) {
    const float* A = (const float*)d_in[0];
    const float* B = (const float*)d_in[1];
    const int n = in_sizes[0] / KDIM;   // 8192

    int NS = 8;
    size_t need = ((size_t)2 * n + (size_t)4 * n * NS + (size_t)8 * n) * sizeof(float);
    if (ws_size < need) NS = 1;

    float* ws   = (float*)d_ws;
    float* invA = ws;
    float* invB = ws + n;
    float4* partial = (float4*)(ws + 2 * (size_t)n);
    float4* tAB     = (float4*)(ws + 2 * (size_t)n + 4 * (size_t)n * NS);
    float4* tBA     = tAB + n;

    dim3 blk(256);
    dim3 ngrid((n + 255) / 256);
    norms_kernel<<<ngrid, blk, 0, stream>>>(A, invA, n);
    norms_kernel<<<ngrid, blk, 0, stream>>>(B, invB, n);

    dim3 grid(n / BM, NS);
    // pass 1: rows = A descriptors, cols = B descriptors
    gemm_top2<<<grid, blk, 0, stream>>>(A, B, invA, invB, partial, n, NS);
    merge_top2<<<ngrid, blk, 0, stream>>>(partial, tAB, n, NS);
    // pass 2: transposed direction
    gemm_top2<<<grid, blk, 0, stream>>>(B, A, invB, invA, partial, n, NS);
    merge_top2<<<ngrid, blk, 0, stream>>>(partial, tBA, n, NS);

    match_kernel<<<ngrid, blk, 0, stream>>>(tAB, tBA, (float*)d_out, n);
}

// Round 2
// 763.365 us; speedup vs baseline: 1.4499x; 1.4499x over previous
//
#include <hip/hip_runtime.h>
#include <hip/hip_bf16.h>
#include <math.h>

#define KDIM 256
#define RATIO_T 0.9f
#define EPS_T 1e-8f

// ---- fused kernel geometry ----
#define FBM 128   // rows per block tile
#define FBN 128   // cols per j-tile
#define FBK 16    // k slab
#define FNS 16    // column chunks (grid.y)

// ---- old fallback geometry ----
#define BM 64
#define BN 64
#define BKS 16

// 1 / ||column i||  for X stored (KDIM x n) row-major (descriptors are columns)
__global__ void norms_kernel(const float* __restrict__ X, float* __restrict__ inv, int n) {
    int i = blockIdx.x * blockDim.x + threadIdx.x;
    if (i >= n) return;
    float s = 0.f;
#pragma unroll 8
    for (int k = 0; k < KDIM; ++k) {
        float v = X[(size_t)k * n + i];
        s += v * v;
    }
    inv[i] = 1.0f / sqrtf(s);
}

// strict total order: larger value first, ties -> lower index (lax.top_k semantics)
__device__ __forceinline__ bool bt(float v, int i, float u, int j) {
    return v > u || (v == u && i < j);
}
__device__ __forceinline__ void ins2(float& a0, int& ai0, float& a1, int& ai1, float v, int i) {
    if (bt(v, i, a0, ai0)) { a1 = a0; ai1 = ai0; a0 = v; ai0 = i; }
    else if (bt(v, i, a1, ai1)) { a1 = v; ai1 = i; }
}
// merge sorted pair (b0,b1) into running sorted pair (a0,a1)
__device__ __forceinline__ void mrg2(float& a0, int& ai0, float& a1, int& ai1,
                                     float b0, int bi0, float b1, int bi1) {
    if (bt(b0, bi0, a0, ai0)) {
        bool keepA0 = bt(a0, ai0, b1, bi1);
        float n1 = keepA0 ? a0 : b1; int ni1 = keepA0 ? ai0 : bi1;
        a0 = b0; ai0 = bi0; a1 = n1; ai1 = ni1;
    } else if (bt(b0, bi0, a1, ai1)) {
        a1 = b0; ai1 = bi0;   // b1 <= b0 <= a1 now, so b1 cannot place
    }
}

// Fused: one pass over sim = (A^T A-normed) @ (B-normed); emits
//   rowPart[r*FNS + s]  : top-2 over cols in chunk s, for each row r   (A->B)
//   colPart[c*NXT + bx] : top-2 over rows in row-tile bx, for each col c (B->A)
__global__ __launch_bounds__(256, 2) void gemm_both_top2(
    const float* __restrict__ A, const float* __restrict__ B,
    const float* __restrict__ invA, const float* __restrict__ invB,
    float4* __restrict__ rowPart, float4* __restrict__ colPart, int n) {
    __shared__ float As[FBK][FBM];
    __shared__ float Bs[FBK][FBN];
    __shared__ float4 colbuf[4][FBN];

    const int t  = threadIdx.x;
    const int tx = t & 15, ty = t >> 4;
    const int bx = blockIdx.x, s = blockIdx.y;
    const int m0 = bx * FBM;
    const int NXT = n / FBM;
    const int chunk = n / FNS;
    const int jbeg = s * chunk;

    // this thread's 8 rows: ty*4+ii (ii<4) and 64+ty*4+(ii-4)
    int rIdx[8]; float qinv[8];
#pragma unroll
    for (int ii = 0; ii < 8; ++ii) {
        int lr = (ii < 4) ? (ty * 4 + ii) : (64 + ty * 4 + ii - 4);
        rIdx[ii] = m0 + lr;
        qinv[ii] = invA[m0 + lr];
    }
    float rb0[8], rb1[8]; int ri0[8], ri1[8];
#pragma unroll
    for (int ii = 0; ii < 8; ++ii) { rb0[ii] = -INFINITY; rb1[ii] = -INFINITY; ri0[ii] = -1; ri1[ii] = -1; }

    // staging slots: 512 float4 per matrix per k-slab, 2 per thread
    const int r0 = t >> 5,          c0 = (t & 31) << 2;
    const int r1 = (t + 256) >> 5,  c1 = (t & 31) << 2;

    for (int jt = jbeg; jt < jbeg + chunk; jt += FBN) {
        float rinv[8]; int cIdx[8];
#pragma unroll
        for (int jj = 0; jj < 8; ++jj) {
            int lc = (jj < 4) ? (tx * 4 + jj) : (64 + tx * 4 + jj - 4);
            cIdx[jj] = jt + lc;
            rinv[jj] = invB[jt + lc];
        }
        float acc[8][8];
#pragma unroll
        for (int ii = 0; ii < 8; ++ii)
#pragma unroll
            for (int jj = 0; jj < 8; ++jj) acc[ii][jj] = 0.f;

        for (int k0 = 0; k0 < KDIM; k0 += FBK) {
            float4 ga0 = *reinterpret_cast<const float4*>(&A[(size_t)(k0 + r0) * n + m0 + c0]);
            float4 ga1 = *reinterpret_cast<const float4*>(&A[(size_t)(k0 + r1) * n + m0 + c1]);
            float4 gb0 = *reinterpret_cast<const float4*>(&B[(size_t)(k0 + r0) * n + jt + c0]);
            float4 gb1 = *reinterpret_cast<const float4*>(&B[(size_t)(k0 + r1) * n + jt + c1]);
            __syncthreads();   // prior LDS reads done
            *reinterpret_cast<float4*>(&As[r0][c0]) = ga0;
            *reinterpret_cast<float4*>(&As[r1][c1]) = ga1;
            *reinterpret_cast<float4*>(&Bs[r0][c0]) = gb0;
            *reinterpret_cast<float4*>(&Bs[r1][c1]) = gb1;
            __syncthreads();
#pragma unroll
            for (int k = 0; k < FBK; ++k) {
                float4 a0 = *reinterpret_cast<const float4*>(&As[k][ty * 4]);
                float4 a1 = *reinterpret_cast<const float4*>(&As[k][64 + ty * 4]);
                float4 b0 = *reinterpret_cast<const float4*>(&Bs[k][tx * 4]);
                float4 b1 = *reinterpret_cast<const float4*>(&Bs[k][64 + tx * 4]);
                float av[8] = {a0.x, a0.y, a0.z, a0.w, a1.x, a1.y, a1.z, a1.w};
                float bv[8] = {b0.x, b0.y, b0.z, b0.w, b1.x, b1.y, b1.z, b1.w};
#pragma unroll
                for (int ii = 0; ii < 8; ++ii)
#pragma unroll
                    for (int jj = 0; jj < 8; ++jj) acc[ii][jj] += av[ii] * bv[jj];
            }
        }
        // scale to cosine sim: same op order as the verified round-1 kernel
#pragma unroll
        for (int ii = 0; ii < 8; ++ii)
#pragma unroll
            for (int jj = 0; jj < 8; ++jj) acc[ii][jj] = acc[ii][jj] * qinv[ii] * rinv[jj];

        // ---- row top-2 (reduce over cols: tx lane bits 1,2,4,8) ----
#pragma unroll
        for (int ii = 0; ii < 8; ++ii) {
            float b0 = -INFINITY, b1 = -INFINITY; int i0 = -1, i1 = -1;
#pragma unroll
            for (int jj = 0; jj < 8; ++jj) ins2(b0, i0, b1, i1, acc[ii][jj], cIdx[jj]);
#pragma unroll
            for (int m = 1; m <= 8; m <<= 1) {
                float o0 = __shfl_xor(b0, m), o1 = __shfl_xor(b1, m);
                int oi0 = __shfl_xor(i0, m), oi1 = __shfl_xor(i1, m);
                mrg2(b0, i0, b1, i1, o0, oi0, o1, oi1);
            }
            mrg2(rb0[ii], ri0[ii], rb1[ii], ri1[ii], b0, i0, b1, i1);
        }

        // ---- col top-2 (reduce over rows: ty bits 16,32 in-wave, then LDS across waves) ----
#pragma unroll
        for (int jj = 0; jj < 8; ++jj) {
            float b0 = -INFINITY, b1 = -INFINITY; int i0 = -1, i1 = -1;
#pragma unroll
            for (int ii = 0; ii < 8; ++ii) ins2(b0, i0, b1, i1, acc[ii][jj], rIdx[ii]);
#pragma unroll
            for (int m = 16; m <= 32; m <<= 1) {
                float o0 = __shfl_xor(b0, m), o1 = __shfl_xor(b1, m);
                int oi0 = __shfl_xor(i0, m), oi1 = __shfl_xor(i1, m);
                mrg2(b0, i0, b1, i1, o0, oi0, o1, oi1);
            }
            if ((t & 48) == 0) {
                int lc = (jj < 4) ? (tx * 4 + jj) : (64 + tx * 4 + jj - 4);
                colbuf[t >> 6][lc] = make_float4(b0, b1, (float)i0, (float)i1);
            }
        }
        __syncthreads();
        if (t < FBN) {
            float a0 = -INFINITY, a1 = -INFINITY; int ai0 = -1, ai1 = -1;
#pragma unroll
            for (int w = 0; w < 4; ++w) {
                float4 p = colbuf[w][t];
                mrg2(a0, ai0, a1, ai1, p.x, (int)p.z, p.y, (int)p.w);
            }
            colPart[(size_t)(jt + t) * NXT + bx] = make_float4(a0, a1, (float)ai0, (float)ai1);
        }
    }
    if (tx == 0) {
#pragma unroll
        for (int ii = 0; ii < 8; ++ii)
            rowPart[(size_t)rIdx[ii] * FNS + s] =
                make_float4(rb0[ii], rb1[ii], (float)ri0[ii], (float)ri1[ii]);
    }
}

// generic partial-top2 merge: part[i*cnt + s], index tiebreak
__global__ void merge_part(const float4* __restrict__ part, float4* __restrict__ out,
                           int n, int cnt) {
    int i = blockIdx.x * blockDim.x + threadIdx.x;
    if (i >= n) return;
    float a0 = -INFINITY, a1 = -INFINITY; int ai0 = -1, ai1 = -1;
    for (int s = 0; s < cnt; ++s) {
        float4 p = part[(size_t)i * cnt + s];
        mrg2(a0, ai0, a1, ai1, p.x, (int)p.z, p.y, (int)p.w);
    }
    out[i] = make_float4(a0, a1, (float)ai0, (float)ai1);
}

// ---------------- old (fallback) two-pass kernel ----------------
__global__ __launch_bounds__(256) void gemm_top2(
    const float* __restrict__ Q, const float* __restrict__ Rm,
    const float* __restrict__ invQ, const float* __restrict__ invR,
    float4* __restrict__ partial, int n, int NS) {
    __shared__ float As2[BKS][BM];
    __shared__ float Bs2[BKS][BN];
    __shared__ float Sm[BM][BN + 1];

    const int t  = threadIdx.x;
    const int tx = t & 15;
    const int ty = t >> 4;
    const int m0 = blockIdx.x * BM;
    const int s  = blockIdx.y;
    const int chunk = n / NS;
    const int jbeg = s * chunk;
    const int jend = jbeg + chunk;
    const int lk = t >> 4;
    const int li = (t & 15) * 4;

    float best0 = -INFINITY, best1 = -INFINITY;
    int bi0 = -1, bi1 = -1;
    const float qinv = (t < BM) ? invQ[m0 + t] : 0.f;

    for (int jt = jbeg; jt < jend; jt += BN) {
        float acc[4][4];
#pragma unroll
        for (int a = 0; a < 4; ++a)
#pragma unroll
            for (int b = 0; b < 4; ++b) acc[a][b] = 0.f;
        for (int k0 = 0; k0 < KDIM; k0 += BKS) {
            float4 ga = *reinterpret_cast<const float4*>(&Q[(size_t)(k0 + lk) * n + m0 + li]);
            float4 gb = *reinterpret_cast<const float4*>(&Rm[(size_t)(k0 + lk) * n + jt + li]);
            __syncthreads();
            *reinterpret_cast<float4*>(&As2[lk][li]) = ga;
            *reinterpret_cast<float4*>(&Bs2[lk][li]) = gb;
            __syncthreads();
#pragma unroll
            for (int k = 0; k < BKS; ++k) {
                float4 a4 = *reinterpret_cast<const float4*>(&As2[k][ty * 4]);
                float4 b4 = *reinterpret_cast<const float4*>(&Bs2[k][tx * 4]);
                float ar[4] = {a4.x, a4.y, a4.z, a4.w};
                float br[4] = {b4.x, b4.y, b4.z, b4.w};
#pragma unroll
                for (int ii = 0; ii < 4; ++ii)
#pragma unroll
                    for (int jj = 0; jj < 4; ++jj) acc[ii][jj] += ar[ii] * br[jj];
            }
        }
#pragma unroll
        for (int ii = 0; ii < 4; ++ii)
#pragma unroll
            for (int jj = 0; jj < 4; ++jj)
                Sm[ty * 4 + ii][tx * 4 + jj] = acc[ii][jj];
        __syncthreads();
        if (t < BM) {
#pragma unroll 4
            for (int j = 0; j < BN; ++j) {
                float v = Sm[t][j] * qinv * invR[jt + j];
                if (v > best0)      { best1 = best0; bi1 = bi0; best0 = v; bi0 = jt + j; }
                else if (v > best1) { best1 = v;     bi1 = jt + j; }
            }
        }
        __syncthreads();
    }
    if (t < BM)
        partial[(size_t)(m0 + t) * NS + s] = make_float4(best0, best1, (float)bi0, (float)bi1);
}

__global__ void match_kernel(const float4* __restrict__ tAB,
                             const float4* __restrict__ tBA,
                             float* __restrict__ out, int n) {
    int i = blockIdx.x * blockDim.x + threadIdx.x;
    if (i >= n) return;
    float4 a = tAB[i];
    int j0 = (int)a.z;
    float d0 = 2.0f - 2.0f * a.x;
    float d1 = 2.0f - 2.0f * a.y;
    float r12 = d0 / (d1 + EPS_T);
    float4 b = tBA[j0];
    int nn21 = (int)b.z;
    float e0 = 2.0f - 2.0f * b.x;
    float e1 = 2.0f - 2.0f * b.y;
    float r21 = e0 / (e1 + EPS_T);
    bool m = (i == nn21) && (r12 <= RATIO_T) && (r21 <= RATIO_T);
    out[2 * i]     = m ? (float)i  : -1.0f;
    out[2 * i + 1] = m ? (float)j0 : -1.0f;
    out[2 * (size_t)n + i] = m ? a.x : 0.0f;
    out[3 * (size_t)n + i] = m ? 1.0f : 0.0f;
}

extern "C" void kernel_launch(void* const* d_in, const int* in_sizes, int n_in,
                              void* d_out, int out_size, void* d_ws, size_t ws_size,
                              hipStream_t stream) {
    const float* A = (const float*)d_in[0];
    const float* B = (const float*)d_in[1];
    const int n = in_sizes[0] / KDIM;   // 8192

    float* ws = (float*)d_ws;
    dim3 blk(256);
    dim3 ngrid((n + 255) / 256);

    const int NXT = n / FBM;
    size_t needF = (size_t)2 * n * sizeof(float) +
                   ((size_t)n * FNS + (size_t)n * NXT + 2 * (size_t)n) * sizeof(float4);
    bool shape_ok = (n % (FBM * 1) == 0) && (n % FNS == 0) && ((n / FNS) % FBN == 0);

    if (shape_ok && ws_size >= needF) {
        float* invA = ws;
        float* invB = ws + n;
        float4* rowPart = (float4*)(ws + 2 * (size_t)n);
        float4* colPart = rowPart + (size_t)n * FNS;
        float4* tAB     = colPart + (size_t)n * NXT;
        float4* tBA     = tAB + n;

        norms_kernel<<<ngrid, blk, 0, stream>>>(A, invA, n);
        norms_kernel<<<ngrid, blk, 0, stream>>>(B, invB, n);

        dim3 grid(NXT, FNS);
        gemm_both_top2<<<grid, blk, 0, stream>>>(A, B, invA, invB, rowPart, colPart, n);
        merge_part<<<ngrid, blk, 0, stream>>>(rowPart, tAB, n, FNS);
        merge_part<<<ngrid, blk, 0, stream>>>(colPart, tBA, n, NXT);
        match_kernel<<<ngrid, blk, 0, stream>>>(tAB, tBA, (float*)d_out, n);
    } else {
        // fallback: two-pass (round-1 verified path)
        int NS = 8;
        size_t need = ((size_t)2 * n + (size_t)4 * n * NS + (size_t)8 * n) * sizeof(float);
        if (ws_size < need) NS = 1;
        float* invA = ws;
        float* invB = ws + n;
        float4* partial = (float4*)(ws + 2 * (size_t)n);
        float4* tAB     = partial + (size_t)n * NS;
        float4* tBA     = tAB + n;

        norms_kernel<<<ngrid, blk, 0, stream>>>(A, invA, n);
        norms_kernel<<<ngrid, blk, 0, stream>>>(B, invB, n);
        dim3 grid(n / BM, NS);
        gemm_top2<<<grid, blk, 0, stream>>>(A, B, invA, invB, partial, n, NS);
        merge_part<<<ngrid, blk, 0, stream>>>(partial, tAB, n, NS);
        gemm_top2<<<grid, blk, 0, stream>>>(B, A, invB, invA, partial, n, NS);
        merge_part<<<ngrid, blk, 0, stream>>>(partial, tBA, n, NS);
        match_kernel<<<ngrid, blk, 0, stream>>>(tAB, tBA, (float*)d_out, n);
    }
}

// Round 5
// 430.594 us; speedup vs baseline: 2.5703x; 1.7728x over previous
//
#include <hip/hip_runtime.h>
#include <hip/hip_bf16.h>
#include <math.h>

#define KDIM 256
#define RATIO_T 0.9f
#define EPS_T 1e-8f
#define FNS 16

// fallback geometry (round-2 verified)
#define FBM 128
#define FBN 128
#define FBK 16
#define BM 64
#define BN 64
#define BKS 16

typedef _Float16 f16x8 __attribute__((ext_vector_type(8)));
typedef float f32x4 __attribute__((ext_vector_type(4)));
typedef unsigned short ushort_t;

__device__ __forceinline__ void gld_lds16(const void* g, void* l) {
    __builtin_amdgcn_global_load_lds(
        (const __attribute__((address_space(1))) unsigned int*)g,
        (__attribute__((address_space(3))) unsigned int*)l, 16, 0, 0);
}

// 1 / ||column i||  for X stored (KDIM x n) row-major
__global__ void norms_kernel(const float* __restrict__ X, float* __restrict__ inv, int n) {
    int i = blockIdx.x * blockDim.x + threadIdx.x;
    if (i >= n) return;
    float s = 0.f;
#pragma unroll 8
    for (int k = 0; k < KDIM; ++k) {
        float v = X[(size_t)k * n + i];
        s += v * v;
    }
    inv[i] = 1.0f / sqrtf(s);
}

// fp16 split: h = fp16(x), l6 = fp16((x-h)*64), written in GEMM-frag-order layout.
// frag layout: 16B unit index = ((bm*8 + s)*8 + fm)*64 + g*16 + lm
//   where element [k][i]: bm=i>>7, fm=(i>>4)&7, lm=i&15, s=k>>5, g=(k>>3)&3, e=k&7
__global__ void split_kernel(const float* __restrict__ X, ushort_t* __restrict__ Xh,
                             ushort_t* __restrict__ Xl6, int n) {
    int tid = blockIdx.x * blockDim.x + threadIdx.x;   // n*32 threads total
    int lane = tid & 63;
    int rest = tid >> 6;
    int kg = rest & 31, iblk = rest >> 5;
    int i = iblk * 64 + lane;
    if (i >= n) return;
    float x[8];
#pragma unroll
    for (int e = 0; e < 8; ++e) x[e] = X[(size_t)(kg * 8 + e) * n + i];
    union { ushort_t us[8]; uint4 v; } ph, pl;
#pragma unroll
    for (int e = 0; e < 8; ++e) {
        _Float16 hh = (_Float16)x[e];
        float r = x[e] - (float)hh;
        _Float16 ll = (_Float16)(r * 64.0f);
        ph.us[e] = __builtin_bit_cast(ushort_t, hh);
        pl.us[e] = __builtin_bit_cast(ushort_t, ll);
    }
    int bm = i >> 7, fm = (i >> 4) & 7, lmm = i & 15;
    int sk = kg >> 2, gg = kg & 3;
    size_t off16 = ((((size_t)bm * 8 + sk) * 8 + fm) * 64) + gg * 16 + lmm;
    ((uint4*)Xh)[off16] = ph.v;
    ((uint4*)Xl6)[off16] = pl.v;
}

// top-2 helpers WITHOUT index tie-break (ties are masked by the ratio test)
__device__ __forceinline__ void ins2v(float v, int i, float& b0, float& b1, int& i0, int& i1) {
    bool g0 = v > b0;
    bool g1 = v > b1;
    float nb1 = g0 ? b0 : (g1 ? v : b1);
    int   ni1 = g0 ? i0 : (g1 ? i : i1);
    b0 = g0 ? v : b0;
    i0 = g0 ? i : i0;
    b1 = nb1; i1 = ni1;
}
__device__ __forceinline__ void mrg2v(float& a0, float& a1, int& ai0, int& ai1,
                                      float b0, float b1, int bi0, int bi1) {
    bool f = b0 > a0;
    float n0 = f ? b0 : a0; int n0i = f ? bi0 : ai0;
    float s1 = f ? a0 : b0; int s1i = f ? ai0 : bi0;
    float s2 = f ? b1 : a1; int s2i = f ? bi1 : ai1;
    bool h = s2 > s1;
    a0 = n0; ai0 = n0i;
    a1 = h ? s2 : s1; ai1 = h ? s2i : s1i;
}

// MFMA GEMM (fp16 split, Keff=768) + fused both-direction top-2.
// grid = (n/128, FNS), block 256 (4 waves of 64x64 output).
__global__ __launch_bounds__(256) void mfma_top2(
    const ushort_t* __restrict__ Ah, const ushort_t* __restrict__ Al6,
    const ushort_t* __restrict__ Bh, const ushort_t* __restrict__ Bl6,
    const float* __restrict__ invA, const float* __restrict__ invB,
    float4* __restrict__ rowPart, float4* __restrict__ colPart, int n) {
    __shared__ __align__(16) ushort_t Abuf[2][4096];   // 8 frags * 64 lanes * 8 halves
    __shared__ __align__(16) ushort_t Bbuf[2][4096];
    __shared__ float4 colbuf[2][128];

    const int t = threadIdx.x, lane = t & 63, w = t >> 6;
    const int wm = w & 1, wn = w >> 1;
    const int lm = lane & 15, g = lane >> 4;
    const int bx = blockIdx.x, s = blockIdx.y;
    const int m0 = bx * 128;
    const int NXT = n >> 7;
    const int chunk = n / FNS;
    const int jbeg = s * chunk;
    const int NJT = chunk >> 7;

    // preload invA for this wave's rows
    float rA[4][4];
#pragma unroll
    for (int fm = 0; fm < 4; ++fm)
#pragma unroll
        for (int r = 0; r < 4; ++r)
            rA[fm][r] = invA[m0 + wm * 64 + fm * 16 + g * 4 + r];

    // running row top-2 (sharded: lane lm owns (fm=lm>>2, r=lm&3))
    float rr0 = -INFINITY, rr1 = -INFINITY; int rri0 = -1, rri1 = -1;

    int cur = 0;
    // prologue: stage (j-tile 0, slab 0) into buf 0   (slab 0 -> phase hh)
    {
        const char* As = (const char*)Ah;
        const char* Bs = (const char*)Bh;
        size_t ab = ((size_t)bx * 8 + 0) * 8192;
        size_t bb = ((size_t)(jbeg >> 7) * 8 + 0) * 8192;
#pragma unroll
        for (int c = 0; c < 2; ++c) {
            gld_lds16(As + ab + (w * 2 + c) * 1024 + (size_t)lane * 16, &Abuf[0][(w * 2 + c) * 512]);
            gld_lds16(Bs + bb + (w * 2 + c) * 1024 + (size_t)lane * 16, &Bbuf[0][(w * 2 + c) * 512]);
        }
    }
    __syncthreads();   // drains vmcnt(0) before barrier

    for (int ji = 0; ji < NJT; ++ji) {
        const int jt = jbeg + ji * 128;
        f32x4 acc[4][4];
#pragma unroll
        for (int fm = 0; fm < 4; ++fm)
#pragma unroll
            for (int fn = 0; fn < 4; ++fn)
                acc[fm][fn] = f32x4{0.f, 0.f, 0.f, 0.f};

        for (int ss = 0; ss < 24; ++ss) {
            // stage next slab (or first slab of next j-tile) into buf cur^1
            int ns = -1, njcb = 0;
            if (ss < 23) { ns = ss + 1; njcb = jt >> 7; }
            else if (ji + 1 < NJT) { ns = 0; njcb = (jt + 128) >> 7; }
            if (ns >= 0) {
                int p = ns >> 3, sk = ns & 7;
                const char* As = (const char*)(p == 1 ? Al6 : Ah);
                const char* Bs = (const char*)(p == 2 ? Bl6 : Bh);
                size_t ab = ((size_t)bx * 8 + sk) * 8192;
                size_t bb = ((size_t)njcb * 8 + sk) * 8192;
                ushort_t* Ad = Abuf[cur ^ 1];
                ushort_t* Bd = Bbuf[cur ^ 1];
#pragma unroll
                for (int c = 0; c < 2; ++c) {
                    gld_lds16(As + ab + (w * 2 + c) * 1024 + (size_t)lane * 16, Ad + (w * 2 + c) * 512);
                    gld_lds16(Bs + bb + (w * 2 + c) * 1024 + (size_t)lane * 16, Bd + (w * 2 + c) * 512);
                }
            }
            // compute current slab from buf cur
            {
                int p = ss >> 3;
                f16x8 af[4], bf[4];
#pragma unroll
                for (int fm = 0; fm < 4; ++fm)
                    af[fm] = *(const f16x8*)(&Abuf[cur][((wm * 4 + fm) * 64 + lane) * 8]);
#pragma unroll
                for (int fn = 0; fn < 4; ++fn)
                    bf[fn] = *(const f16x8*)(&Bbuf[cur][((wn * 4 + fn) * 64 + lane) * 8]);
                if (p == 2) {
#pragma unroll
                    for (int fm = 0; fm < 4; ++fm) af[fm] = af[fm] * (_Float16)0.015625f;
                }
                if (p == 1) {
#pragma unroll
                    for (int fn = 0; fn < 4; ++fn) bf[fn] = bf[fn] * (_Float16)0.015625f;
                }
#pragma unroll
                for (int fm = 0; fm < 4; ++fm)
#pragma unroll
                    for (int fn = 0; fn < 4; ++fn)
                        acc[fm][fn] = __builtin_amdgcn_mfma_f32_16x16x32_f16(
                            af[fm], bf[fn], acc[fm][fn], 0, 0, 0);
            }
            __syncthreads();
            cur ^= 1;
        }

        // ---- epilogue: scale + both-direction top-2 ----
        float rB[4]; int cI[4];
#pragma unroll
        for (int fn = 0; fn < 4; ++fn) {
            int c = jt + wn * 64 + fn * 16 + lm;
            cI[fn] = c; rB[fn] = invB[c];
        }
#pragma unroll
        for (int fm = 0; fm < 4; ++fm)
#pragma unroll
            for (int fn = 0; fn < 4; ++fn)
#pragma unroll
                for (int r = 0; r < 4; ++r)
                    acc[fm][fn][r] = acc[fm][fn][r] * rA[fm][r] * rB[fn];

        // row top-2 (reduce over cols: lane bits 0-3)
#pragma unroll
        for (int fm = 0; fm < 4; ++fm) {
#pragma unroll
            for (int r = 0; r < 4; ++r) {
                float b0 = -INFINITY, b1 = -INFINITY; int i0 = -1, i1 = -1;
#pragma unroll
                for (int fn = 0; fn < 4; ++fn) ins2v(acc[fm][fn][r], cI[fn], b0, b1, i0, i1);
#pragma unroll
                for (int m = 1; m <= 8; m <<= 1) {
                    float o0 = __shfl_xor(b0, m), o1 = __shfl_xor(b1, m);
                    int oi0 = __shfl_xor(i0, m), oi1 = __shfl_xor(i1, m);
                    mrg2v(b0, b1, i0, i1, o0, o1, oi0, oi1);
                }
                float t0 = rr0, t1 = rr1; int ti0 = rri0, ti1 = rri1;
                mrg2v(t0, t1, ti0, ti1, b0, b1, i0, i1);
                bool own = (lm == fm * 4 + r);
                rr0 = own ? t0 : rr0; rr1 = own ? t1 : rr1;
                rri0 = own ? ti0 : rri0; rri1 = own ? ti1 : rri1;
            }
        }
        // col top-2 (reduce over rows: in-lane 16 + lane bits 4,5 + cross-wm via LDS)
#pragma unroll
        for (int fn = 0; fn < 4; ++fn) {
            float b0 = -INFINITY, b1 = -INFINITY; int i0 = -1, i1 = -1;
#pragma unroll
            for (int fm = 0; fm < 4; ++fm)
#pragma unroll
                for (int r = 0; r < 4; ++r)
                    ins2v(acc[fm][fn][r], m0 + wm * 64 + fm * 16 + g * 4 + r, b0, b1, i0, i1);
#pragma unroll
            for (int m = 16; m <= 32; m <<= 1) {
                float o0 = __shfl_xor(b0, m), o1 = __shfl_xor(b1, m);
                int oi0 = __shfl_xor(i0, m), oi1 = __shfl_xor(i1, m);
                mrg2v(b0, b1, i0, i1, o0, o1, oi0, oi1);
            }
            if (g == 0) colbuf[wm][wn * 64 + fn * 16 + lm] = make_float4(b0, b1, (float)i0, (float)i1);
        }
        __syncthreads();
        if (t < 128) {
            float4 u = colbuf[0][t], v = colbuf[1][t];
            float a0 = u.x, a1 = u.y; int ai0 = (int)u.z, ai1 = (int)u.w;
            mrg2v(a0, a1, ai0, ai1, v.x, v.y, (int)v.z, (int)v.w);
            colPart[(size_t)(jt + t) * NXT + bx] = make_float4(a0, a1, (float)ai0, (float)ai1);
        }
    }
    // write sharded row partials (one per lane)
    {
        int fm_s = lm >> 2, r_s = lm & 3;
        int row_s = m0 + wm * 64 + fm_s * 16 + g * 4 + r_s;
        rowPart[(size_t)row_s * (2 * FNS) + s * 2 + wn] =
            make_float4(rr0, rr1, (float)rri0, (float)rri1);
    }
}

// ---- old helpers with float-idx (used by merge/match + fallback) ----
__device__ __forceinline__ bool bt(float v, int i, float u, int j) {
    return v > u || (v == u && i < j);
}
__device__ __forceinline__ void mrg2(float& a0, int& ai0, float& a1, int& ai1,
                                     float b0, int bi0, float b1, int bi1) {
    if (bt(b0, bi0, a0, ai0)) {
        bool keepA0 = bt(a0, ai0, b1, bi1);
        float n1 = keepA0 ? a0 : b1; int ni1 = keepA0 ? ai0 : bi1;
        a0 = b0; ai0 = bi0; a1 = n1; ai1 = ni1;
    } else if (bt(b0, bi0, a1, ai1)) {
        a1 = b0; ai1 = bi0;
    }
}

__global__ void merge_part(const float4* __restrict__ part, float4* __restrict__ out,
                           int n, int cnt) {
    int i = blockIdx.x * blockDim.x + threadIdx.x;
    if (i >= n) return;
    float a0 = -INFINITY, a1 = -INFINITY; int ai0 = -1, ai1 = -1;
    for (int s = 0; s < cnt; ++s) {
        float4 p = part[(size_t)i * cnt + s];
        mrg2(a0, ai0, a1, ai1, p.x, (int)p.z, p.y, (int)p.w);
    }
    out[i] = make_float4(a0, a1, (float)ai0, (float)ai1);
}

__global__ void match_kernel(const float4* __restrict__ tAB,
                             const float4* __restrict__ tBA,
                             float* __restrict__ out, int n) {
    int i = blockIdx.x * blockDim.x + threadIdx.x;
    if (i >= n) return;
    float4 a = tAB[i];
    int j0 = (int)a.z;
    float d0 = 2.0f - 2.0f * a.x;
    float d1 = 2.0f - 2.0f * a.y;
    float r12 = d0 / (d1 + EPS_T);
    float4 b = tBA[j0];
    int nn21 = (int)b.z;
    float e0 = 2.0f - 2.0f * b.x;
    float e1 = 2.0f - 2.0f * b.y;
    float r21 = e0 / (e1 + EPS_T);
    bool m = (i == nn21) && (r12 <= RATIO_T) && (r21 <= RATIO_T);
    out[2 * i]     = m ? (float)i  : -1.0f;
    out[2 * i + 1] = m ? (float)j0 : -1.0f;
    out[2 * (size_t)n + i] = m ? a.x : 0.0f;
    out[3 * (size_t)n + i] = m ? 1.0f : 0.0f;
}

// ---------------- round-2 fused fp32 kernel (fallback) ----------------
__device__ __forceinline__ void ins2f(float& a0, int& ai0, float& a1, int& ai1, float v, int i) {
    if (bt(v, i, a0, ai0)) { a1 = a0; ai1 = ai0; a0 = v; ai0 = i; }
    else if (bt(v, i, a1, ai1)) { a1 = v; ai1 = i; }
}

__global__ __launch_bounds__(256, 2) void gemm_both_top2(
    const float* __restrict__ A, const float* __restrict__ B,
    const float* __restrict__ invA, const float* __restrict__ invB,
    float4* __restrict__ rowPart, float4* __restrict__ colPart, int n) {
    __shared__ float As[FBK][FBM];
    __shared__ float Bs[FBK][FBN];
    __shared__ float4 colbuf2[4][FBN];

    const int t  = threadIdx.x;
    const int tx = t & 15, ty = t >> 4;
    const int bx = blockIdx.x, s = blockIdx.y;
    const int m0 = bx * FBM;
    const int NXT = n / FBM;
    const int chunk = n / FNS;
    const int jbeg = s * chunk;

    int rIdx[8]; float qinv[8];
#pragma unroll
    for (int ii = 0; ii < 8; ++ii) {
        int lr = (ii < 4) ? (ty * 4 + ii) : (64 + ty * 4 + ii - 4);
        rIdx[ii] = m0 + lr;
        qinv[ii] = invA[m0 + lr];
    }
    float rb0[8], rb1[8]; int ri0[8], ri1[8];
#pragma unroll
    for (int ii = 0; ii < 8; ++ii) { rb0[ii] = -INFINITY; rb1[ii] = -INFINITY; ri0[ii] = -1; ri1[ii] = -1; }

    const int r0 = t >> 5,          c0 = (t & 31) << 2;
    const int r1 = (t + 256) >> 5,  c1 = (t & 31) << 2;

    for (int jt = jbeg; jt < jbeg + chunk; jt += FBN) {
        float rinv[8]; int cIdx[8];
#pragma unroll
        for (int jj = 0; jj < 8; ++jj) {
            int lc = (jj < 4) ? (tx * 4 + jj) : (64 + tx * 4 + jj - 4);
            cIdx[jj] = jt + lc;
            rinv[jj] = invB[jt + lc];
        }
        float acc[8][8];
#pragma unroll
        for (int ii = 0; ii < 8; ++ii)
#pragma unroll
            for (int jj = 0; jj < 8; ++jj) acc[ii][jj] = 0.f;

        for (int k0 = 0; k0 < KDIM; k0 += FBK) {
            float4 ga0 = *reinterpret_cast<const float4*>(&A[(size_t)(k0 + r0) * n + m0 + c0]);
            float4 ga1 = *reinterpret_cast<const float4*>(&A[(size_t)(k0 + r1) * n + m0 + c1]);
            float4 gb0 = *reinterpret_cast<const float4*>(&B[(size_t)(k0 + r0) * n + jt + c0]);
            float4 gb1 = *reinterpret_cast<const float4*>(&B[(size_t)(k0 + r1) * n + jt + c1]);
            __syncthreads();
            *reinterpret_cast<float4*>(&As[r0][c0]) = ga0;
            *reinterpret_cast<float4*>(&As[r1][c1]) = ga1;
            *reinterpret_cast<float4*>(&Bs[r0][c0]) = gb0;
            *reinterpret_cast<float4*>(&Bs[r1][c1]) = gb1;
            __syncthreads();
#pragma unroll
            for (int k = 0; k < BKS; ++k) {
                float4 a0 = *reinterpret_cast<const float4*>(&As[k][ty * 4]);
                float4 a1 = *reinterpret_cast<const float4*>(&As[k][64 + ty * 4]);
                float4 b0 = *reinterpret_cast<const float4*>(&Bs[k][tx * 4]);
                float4 b1 = *reinterpret_cast<const float4*>(&Bs[k][64 + tx * 4]);
                float av[8] = {a0.x, a0.y, a0.z, a0.w, a1.x, a1.y, a1.z, a1.w};
                float bv[8] = {b0.x, b0.y, b0.z, b0.w, b1.x, b1.y, b1.z, b1.w};
#pragma unroll
                for (int ii = 0; ii < 8; ++ii)
#pragma unroll
                    for (int jj = 0; jj < 8; ++jj) acc[ii][jj] += av[ii] * bv[jj];
            }
        }
#pragma unroll
        for (int ii = 0; ii < 8; ++ii)
#pragma unroll
            for (int jj = 0; jj < 8; ++jj) acc[ii][jj] = acc[ii][jj] * qinv[ii] * rinv[jj];

#pragma unroll
        for (int ii = 0; ii < 8; ++ii) {
            float b0 = -INFINITY, b1 = -INFINITY; int i0 = -1, i1 = -1;
#pragma unroll
            for (int jj = 0; jj < 8; ++jj) ins2f(b0, i0, b1, i1, acc[ii][jj], cIdx[jj]);
#pragma unroll
            for (int m = 1; m <= 8; m <<= 1) {
                float o0 = __shfl_xor(b0, m), o1 = __shfl_xor(b1, m);
                int oi0 = __shfl_xor(i0, m), oi1 = __shfl_xor(i1, m);
                mrg2(b0, i0, b1, i1, o0, oi0, o1, oi1);
            }
            mrg2(rb0[ii], ri0[ii], rb1[ii], ri1[ii], b0, i0, b1, i1);
        }

#pragma unroll
        for (int jj = 0; jj < 8; ++jj) {
            float b0 = -INFINITY, b1 = -INFINITY; int i0 = -1, i1 = -1;
#pragma unroll
            for (int ii = 0; ii < 8; ++ii) ins2f(b0, i0, b1, i1, acc[ii][jj], rIdx[ii]);
#pragma unroll
            for (int m = 16; m <= 32; m <<= 1) {
                float o0 = __shfl_xor(b0, m), o1 = __shfl_xor(b1, m);
                int oi0 = __shfl_xor(i0, m), oi1 = __shfl_xor(i1, m);
                mrg2(b0, i0, b1, i1, o0, oi0, o1, oi1);
            }
            if ((t & 48) == 0) {
                int lc = (jj < 4) ? (tx * 4 + jj) : (64 + tx * 4 + jj - 4);
                colbuf2[t >> 6][lc] = make_float4(b0, b1, (float)i0, (float)i1);
            }
        }
        __syncthreads();
        if (t < FBN) {
            float a0 = -INFINITY, a1 = -INFINITY; int ai0 = -1, ai1 = -1;
#pragma unroll
            for (int ww = 0; ww < 4; ++ww) {
                float4 p = colbuf2[ww][t];
                mrg2(a0, ai0, a1, ai1, p.x, (int)p.z, p.y, (int)p.w);
            }
            colPart[(size_t)(jt + t) * NXT + bx] = make_float4(a0, a1, (float)ai0, (float)ai1);
        }
        __syncthreads();
    }
    if (tx == 0) {
#pragma unroll
        for (int ii = 0; ii < 8; ++ii)
            rowPart[(size_t)rIdx[ii] * FNS + s] =
                make_float4(rb0[ii], rb1[ii], (float)ri0[ii], (float)ri1[ii]);
    }
}

extern "C" void kernel_launch(void* const* d_in, const int* in_sizes, int n_in,
                              void* d_out, int out_size, void* d_ws, size_t ws_size,
                              hipStream_t stream) {
    const float* A = (const float*)d_in[0];
    const float* B = (const float*)d_in[1];
    const int n = in_sizes[0] / KDIM;   // 8192

    dim3 blk(256);
    dim3 ngrid((n + 255) / 256);
    const int NXT = n / 128;

    // MFMA-path workspace requirement
    size_t needM = (size_t)n * 4 * 2                 // invA, invB
                 + (size_t)n * 512 * 4               // Ah, Al6, Bh, Bl6 (fp16, frag-order)
                 + (size_t)n * (2 * FNS) * 16        // rowPart
                 + (size_t)n * NXT * 16              // colPart
                 + (size_t)n * 16 * 2;               // tAB, tBA
    bool mfma_ok = (n % 2048 == 0) && (ws_size >= needM);

    if (mfma_ok) {
        char* p = (char*)d_ws;
        float* invA = (float*)p;       p += (size_t)n * 4;
        float* invB = (float*)p;       p += (size_t)n * 4;
        ushort_t* Ah  = (ushort_t*)p;  p += (size_t)n * 512;
        ushort_t* Al6 = (ushort_t*)p;  p += (size_t)n * 512;
        ushort_t* Bh  = (ushort_t*)p;  p += (size_t)n * 512;
        ushort_t* Bl6 = (ushort_t*)p;  p += (size_t)n * 512;
        float4* rowPart = (float4*)p;  p += (size_t)n * (2 * FNS) * 16;
        float4* colPart = (float4*)p;  p += (size_t)n * NXT * 16;
        float4* tAB = (float4*)p;      p += (size_t)n * 16;
        float4* tBA = (float4*)p;

        norms_kernel<<<ngrid, blk, 0, stream>>>(A, invA, n);
        norms_kernel<<<ngrid, blk, 0, stream>>>(B, invB, n);
        dim3 sgrid((n * 32 + 255) / 256);
        split_kernel<<<sgrid, blk, 0, stream>>>(A, Ah, Al6, n);
        split_kernel<<<sgrid, blk, 0, stream>>>(B, Bh, Bl6, n);

        dim3 grid(n / 128, FNS);
        mfma_top2<<<grid, blk, 0, stream>>>(Ah, Al6, Bh, Bl6, invA, invB, rowPart, colPart, n);

        merge_part<<<ngrid, blk, 0, stream>>>(rowPart, tAB, n, 2 * FNS);
        merge_part<<<ngrid, blk, 0, stream>>>(colPart, tBA, n, NXT);
        match_kernel<<<ngrid, blk, 0, stream>>>(tAB, tBA, (float*)d_out, n);
    } else {
        // fallback: round-2 verified fused fp32 path
        float* ws = (float*)d_ws;
        float* invA = ws;
        float* invB = ws + n;
        float4* rowPart = (float4*)(ws + 2 * (size_t)n);
        float4* colPart = rowPart + (size_t)n * FNS;
        float4* tAB     = colPart + (size_t)n * (n / FBM);
        float4* tBA     = tAB + n;

        norms_kernel<<<ngrid, blk, 0, stream>>>(A, invA, n);
        norms_kernel<<<ngrid, blk, 0, stream>>>(B, invB, n);
        dim3 grid(n / FBM, FNS);
        gemm_both_top2<<<grid, blk, 0, stream>>>(A, B, invA, invB, rowPart, colPart, n);
        merge_part<<<ngrid, blk, 0, stream>>>(rowPart, tAB, n, FNS);
        merge_part<<<ngrid, blk, 0, stream>>>(colPart, tBA, n, n / FBM);
        match_kernel<<<ngrid, blk, 0, stream>>>(tAB, tBA, (float*)d_out, n);
    }
}